// Round 8
// baseline (185.165 us; speedup 1.0000x reference)
//
#include <hip/hip_runtime.h>
#include <hip/hip_fp8.h>
#include <math.h>

// ContrastiveLoss — x (8,128,16,8,8) fp32 (4 MB).
// feats[n,f] = x[b*131072 + f*1024 + r], n=(b<<10)|r, N=8192, F=128.
// loss = 10 + ln( sum_{i!=j} exp(10*dot(x̂_i,x̂_j) - 10) )   (unit rows => s<=10)
//
// Round 17: MEASUREMENT ROUND #2 (clock + R7-gram counters).
// Evidence: gram ≈ 18.5 µs across THREE disjoint structures (spilling
// pipeline R3, de-spilled pipeline R5, no-pipeline R7) — stall-hiding is
// irrelevant => issue-bound. Issue work is ~5 µs @2.4GHz. Hypothesis: the
// core clock stays parked (~600-900 MHz) because the measured region is
// dominated by the 41 µs memory-only harness fill; SMU can't ramp in 25 µs.
// Instruments:
//  * clock_probe: 1 wave, 32768 DEPENDENT fmaf (4 cyc each, clock-invariant
//    cycle count 131072) -> wall time reads gfxclk: 55 µs @2.4GHz vs
//    ~190 µs @700MHz. Decisive.
//  * gram runs REPS=4 (R4-proven carry idiom) to surface the R7 structure's
//    counters (VGPR/Occupancy/MfmaUtil/WRITE_SIZE) in the top-5.
// Both reverted next round; absmax stays 0 (probe writes to unused ws).
//
// fp8 swizzled layout (verified R7/R8, absmax 0): row-group rg=n>>4 (16 rows,
// 2KB). 16B chunk (t8*64 + q*16 + r) holds bytes[half*8+j] =
// x̂[row r][k = t8*64 + half*32 + q*8 + j] — lane q*16+r's A/B fragments for
// k-steps 2*t8 (low 8B) / 2*t8+1 (high 8B) of mfma_f32_16x16x32_fp8_fp8.
// C/D layout dtype-independent: col=lane&15, row=(lane>>4)*4+reg.
//
// ws: partials float[1376] @0; probe scratch float @16384B; Xs @131072.

#define NTILE 8256   // 128*129/2 upper-triangle 64x64 tiles
#define NPBLK 1376   // 8256 / 6 tiles per block
#define GREPS 4      // gram measurement multiplier (revert to 1 after)

typedef __attribute__((ext_vector_type(4))) float f32x4;
typedef __attribute__((ext_vector_type(2))) long i64x2;

#if __has_builtin(__builtin_amdgcn_exp2f)
#define EXP2F(x) __builtin_amdgcn_exp2f(x)
#else
#define EXP2F(x) exp2f(x)
#endif

__device__ inline unsigned int pk_fp8(float f0, float f1, float f2, float f3) {
#if __has_builtin(__builtin_amdgcn_cvt_pk_fp8_f32)
    unsigned int r = 0;
    r = __builtin_amdgcn_cvt_pk_fp8_f32(f0, f1, r, false);  // bytes 0,1
    r = __builtin_amdgcn_cvt_pk_fp8_f32(f2, f3, r, true);   // bytes 2,3
    return r;
#else
    union { unsigned char b[4]; unsigned int u; } v;
    v.b[0] = __hip_fp8_e4m3(f0).__x; v.b[1] = __hip_fp8_e4m3(f1).__x;
    v.b[2] = __hip_fp8_e4m3(f2).__x; v.b[3] = __hip_fp8_e4m3(f3).__x;
    return v.u;
#endif
}

// ---------------------------------------------------------------------------
// Kernel 1: normalize + fp8 swizzle. Block = 32 rows (2 row-groups).
// ---------------------------------------------------------------------------
__global__ __launch_bounds__(256)
void normalize_kernel(const float* __restrict__ x, unsigned char* __restrict__ Xs) {
    __shared__ float ldsf[128][33];
    __shared__ float ssred[8][32];
    __shared__ float invs[32];
    const int tid = threadIdx.x;
    const int b  = blockIdx.x >> 5;
    const int r0 = (blockIdx.x & 31) * 32;
    const int rl = tid & 31, fp = tid >> 5;       // row-in-block, f-slot
    const float* px = x + b * 131072 + r0 + rl;
    float ss = 0.f;
#pragma unroll
    for (int j = 0; j < 16; ++j) {
        int f = fp * 16 + j;
        float v = px[f * 1024];
        ldsf[f][rl] = v;
        ss = fmaf(v, v, ss);
    }
    ssred[fp][rl] = ss;
    __syncthreads();
    if (tid < 32) {
        float s = 0.f;
#pragma unroll
        for (int k = 0; k < 8; ++k) s += ssred[k][tid];
        invs[tid] = 1.0f / fmaxf(sqrtf(s), 1e-12f);
    }
    __syncthreads();
    {   // one 16B chunk per thread, consecutive tid -> consecutive chunks
        const int c   = tid;
        const int rgl = c >> 7;                   // local row-group 0..1
        const int cc  = c & 127;                  // chunk within row-group
        const int t8  = (cc >> 6) & 1, q = (cc >> 4) & 3, r = cc & 15;
        const int row = rgl * 16 + r;             // local row 0..31
        const float inv = invs[row];
        union { unsigned int w[4]; int4 v; } u;
#pragma unroll
        for (int half = 0; half < 2; ++half) {
            const int k0 = t8 * 64 + half * 32 + q * 8;
            u.w[half * 2 + 0] = pk_fp8(ldsf[k0 + 0][row] * inv, ldsf[k0 + 1][row] * inv,
                                       ldsf[k0 + 2][row] * inv, ldsf[k0 + 3][row] * inv);
            u.w[half * 2 + 1] = pk_fp8(ldsf[k0 + 4][row] * inv, ldsf[k0 + 5][row] * inv,
                                       ldsf[k0 + 6][row] * inv, ldsf[k0 + 7][row] * inv);
        }
        const int rgg = blockIdx.x * 2 + rgl;     // global row-group
        ((int4*)Xs)[rgg * 128 + cc] = u.v;
    }
}

// ---------------------------------------------------------------------------
// Kernel 2: R7 no-pipeline gram, repeated `reps` times (carry idiom: a
// data-dependent 0 offsets the Xs base each rep -> no hoist/DCE; each rep
// computes the identical wsum; last rep's value stands).
// ---------------------------------------------------------------------------
__global__ __launch_bounds__(256)
void gram_lse_kernel(const i64x2* __restrict__ Xs0, float* __restrict__ partials,
                     int reps) {
    const int bk = blockIdx.x;
    const int tid = threadIdx.x;
    const int lane = tid & 63, w = tid >> 6;
    const int ga = (w & 1) * 2;                  // A rg offset within tile
    const int gb = (w >> 1) * 2;                 // B rg offset within tile
    const int quad = lane >> 4, colL = lane & 15;
    const float C = 14.426950408889634f;         // 10*log2(e)

    // decode first tile of the run, then the whole 6-tile list
    int L = bk * 6, I0 = 0;
    while (L >= 128 - I0) { L -= 128 - I0; ++I0; }
    int Is[6], Js[6];
    {
        int ii = I0, jj = I0 + L;
#pragma unroll
        for (int s = 0; s < 6; ++s) {
            Is[s] = ii; Js[s] = jj;
            if (++jj == 128) { ++ii; jj = ii; }
        }
    }

    float wsum = 0.f;
    int carry = 0;                                // always 0, data-dependent
    for (int rep = 0; rep < reps; ++rep) {
        const i64x2* __restrict__ Xs = Xs0 + carry;
        wsum = 0.f;

        // A fragments for the first row of the run
        i64x2 av[2][2];
        int IcurA = Is[0];
#pragma unroll
        for (int g = 0; g < 2; ++g)
#pragma unroll
            for (int t8 = 0; t8 < 2; ++t8)
                av[g][t8] = Xs[(Is[0] * 4 + ga + g) * 128 + t8 * 64 + lane];

#pragma unroll
        for (int s = 0; s < 6; ++s) {
            // A reload only when the run crosses a row boundary
            if (Is[s] != IcurA) {
#pragma unroll
                for (int g = 0; g < 2; ++g)
#pragma unroll
                    for (int t8 = 0; t8 < 2; ++t8)
                        av[g][t8] = Xs[(Is[s] * 4 + ga + g) * 128 + t8 * 64 + lane];
                IcurA = Is[s];
            }

            // direct B fragment loads for this tile (no buffering)
            i64x2 bv[2][2];
#pragma unroll
            for (int g = 0; g < 2; ++g)
#pragma unroll
                for (int t8 = 0; t8 < 2; ++t8)
                    bv[g][t8] = Xs[(Js[s] * 4 + gb + g) * 128 + t8 * 64 + lane];

            f32x4 acc[2][2];
#pragma unroll
            for (int i = 0; i < 2; ++i)
#pragma unroll
                for (int j = 0; j < 2; ++j) acc[i][j] = (f32x4){0.f, 0.f, 0.f, 0.f};
#pragma unroll
            for (int t = 0; t < 4; ++t) {            // K-steps of 32
                const int th = t >> 1, tl = t & 1;   // compile-time after unroll
                long aL[2], bL[2];
#pragma unroll
                for (int g = 0; g < 2; ++g) {
                    aL[g] = av[g][th][tl];
                    bL[g] = bv[g][th][tl];
                }
#pragma unroll
                for (int i = 0; i < 2; ++i)
#pragma unroll
                    for (int j = 0; j < 2; ++j)
                        acc[i][j] = __builtin_amdgcn_mfma_f32_16x16x32_fp8_fp8(
                            aL[i], bL[j], acc[i][j], 0, 0, 0);
            }

            // C/D: col=lane&15, row=(lane>>4)*4+reg (verified)
            const bool diagT = (Is[s] == Js[s]);
            float lsum = 0.f;
#pragma unroll
            for (int i = 0; i < 2; ++i) {
                const int rbase = (ga + i) * 16 + quad * 4;   // row within tile
#pragma unroll
                for (int j = 0; j < 2; ++j) {
                    const int cbase = (gb + j) * 16 + colL;   // col within tile
#pragma unroll
                    for (int g = 0; g < 4; ++g) {
                        if (diagT && (rbase + g == cbase)) continue;
                        lsum += EXP2F(fmaf(C, acc[i][j][g], -C));
                    }
                }
            }
            wsum += diagT ? lsum : 2.0f * lsum;      // symmetry weight
        }
        carry = (int)(wsum * 0.0f);               // 0, depends on this rep
    }

#pragma unroll
    for (int o = 32; o > 0; o >>= 1) wsum += __shfl_down(wsum, o, 64);
    __shared__ float red[4];
    if (lane == 0) red[w] = wsum;
    __syncthreads();
    if (tid == 0) partials[bk] = red[0] + red[1] + red[2] + red[3];
}

// ---------------------------------------------------------------------------
// Kernel 3: out = 10 + ln(sum of 1376 partials), f64 accumulation.
// ---------------------------------------------------------------------------
__global__ __launch_bounds__(256)
void final_kernel(const float* __restrict__ partials, float* __restrict__ out) {
    double s = 0.0;
    for (int i = threadIdx.x; i < NPBLK; i += 256) s += (double)partials[i];
#pragma unroll
    for (int o = 32; o > 0; o >>= 1) s += __shfl_down(s, o, 64);
    __shared__ double red[4];
    if ((threadIdx.x & 63) == 0) red[threadIdx.x >> 6] = s;
    __syncthreads();
    if (threadIdx.x == 0)
        out[0] = (float)(10.0 + log(red[0] + red[1] + red[2] + red[3]));
}

// ---------------------------------------------------------------------------
// Clock probe: 1 wave, 32768 strictly dependent fmaf (latency 4 cyc each,
// clock-invariant 131072-cycle chain). Wall time in rocprof reads gfxclk:
// ~55 µs @2.4 GHz, ~190 µs @700 MHz. Writes to unused ws slot (stays live).
// ---------------------------------------------------------------------------
__global__ __launch_bounds__(64)
void clock_probe(const float* __restrict__ x, float* __restrict__ scratch) {
    float a = x[threadIdx.x] * 1e-38f + 0.999999f;   // ~1, data-dependent
    float b = 0.f;
    for (int i = 0; i < 2048; ++i) {
#pragma unroll
        for (int j = 0; j < 16; ++j) b = fmaf(b, a, 1.0f);  // dependent chain
    }
    scratch[threadIdx.x] = b;                         // keep live
}

extern "C" void kernel_launch(void* const* d_in, const int* in_sizes, int n_in,
                              void* d_out, int out_size, void* d_ws, size_t ws_size,
                              hipStream_t stream) {
    const float* x = (const float*)d_in[0];
    float* out = (float*)d_out;
    float* partials = (float*)d_ws;                         // 1376 floats
    float* probe_scr = (float*)((char*)d_ws + 16384);       // unused by final
    unsigned char* Xs = (unsigned char*)d_ws + 131072;      // 1MB fp8 X̂

    normalize_kernel<<<256, 256, 0, stream>>>(x, Xs);
    gram_lse_kernel<<<NPBLK, 256, 0, stream>>>((const i64x2*)Xs, partials, GREPS);
    final_kernel<<<1, 256, 0, stream>>>(partials, out);
    clock_probe<<<1, 64, 0, stream>>>(x, probe_scr);
}

// Round 9
// 70.273 us; speedup vs baseline: 2.6350x; 2.6350x over previous
//
#include <hip/hip_runtime.h>
#include <hip/hip_fp8.h>
#include <math.h>

// ContrastiveLoss — x (8,128,16,8,8) fp32 (4 MB).
// feats[n,f] = x[b*131072 + f*1024 + r], n=(b<<10)|r, N=8192, F=128.
// loss = 10 + ln( sum_{i!=j} exp(10*dot(x̂_i,x̂_j) - 10) )   (unit rows => s<=10)
//
// Round 18: LDS MACRO-TILE gram. R17 measurements: effective gfxclk ~1.35GHz
// (97µs dependent-FMA probe); gram cold rep = 18.5 µs vs warm rep = 5.4 µs
// -> 13 µs is first-touch latency of Xs (cross-XCD cold misses, too little
// MLP); warm 5.4 µs matches the L2-BW model (154 MB panel re-reads: every
// panel fetched independently by 2 waves, zero block-level reuse).
// Fix both: 128x128 macro-tile per block (2080 = 64*65/2 blocks). Stage A+B
// panels (16KB each, CONTIGUOUS slices of Xs) into LDS via 8 independent
// 16B/thread copies (deep MLP on cold misses), then 4 waves compute the
// 2x2 sub-tiles from LDS. Global traffic 154 -> 67 MB. Straight-line
// register use (~90 VGPR, no rotating indexed buffers = no spill trigger).
// Sub-tile symmetry: off-diag macro: all 4 subs x2; diag macro: (0,0),(1,1)
// diag-skip x1, (0,1) x2, (1,0) skipped. Total work identical (8256 tiles).
//
// fp8 swizzled layout (verified R7/R8, absmax 0): row-group rg=n>>4 (16 rows,
// 2KB). 16B chunk (t8*64 + q*16 + r) holds bytes[half*8+j] =
// x̂[row r][k = t8*64 + half*32 + q*8 + j] — lane q*16+r's A/B fragments for
// k-steps 2*t8 (low 8B) / 2*t8+1 (high 8B) of mfma_f32_16x16x32_fp8_fp8.
// C/D layout dtype-independent: col=lane&15, row=(lane>>4)*4+reg.
//
// ws: partials float[2080] @0; Xs fp8[8192*128] @131072 (1MB).

#define NMACR 2080   // 64*65/2 upper-triangle 128x128 macro-tiles

typedef __attribute__((ext_vector_type(4))) float f32x4;
typedef __attribute__((ext_vector_type(2))) long i64x2;

#if __has_builtin(__builtin_amdgcn_exp2f)
#define EXP2F(x) __builtin_amdgcn_exp2f(x)
#else
#define EXP2F(x) exp2f(x)
#endif

__device__ inline unsigned int pk_fp8(float f0, float f1, float f2, float f3) {
#if __has_builtin(__builtin_amdgcn_cvt_pk_fp8_f32)
    unsigned int r = 0;
    r = __builtin_amdgcn_cvt_pk_fp8_f32(f0, f1, r, false);  // bytes 0,1
    r = __builtin_amdgcn_cvt_pk_fp8_f32(f2, f3, r, true);   // bytes 2,3
    return r;
#else
    union { unsigned char b[4]; unsigned int u; } v;
    v.b[0] = __hip_fp8_e4m3(f0).__x; v.b[1] = __hip_fp8_e4m3(f1).__x;
    v.b[2] = __hip_fp8_e4m3(f2).__x; v.b[3] = __hip_fp8_e4m3(f3).__x;
    return v.u;
#endif
}

// ---------------------------------------------------------------------------
// Kernel 1: normalize + fp8 swizzle. Block = 32 rows (2 row-groups).
// ---------------------------------------------------------------------------
__global__ __launch_bounds__(256)
void normalize_kernel(const float* __restrict__ x, unsigned char* __restrict__ Xs) {
    __shared__ float ldsf[128][33];
    __shared__ float ssred[8][32];
    __shared__ float invs[32];
    const int tid = threadIdx.x;
    const int b  = blockIdx.x >> 5;
    const int r0 = (blockIdx.x & 31) * 32;
    const int rl = tid & 31, fp = tid >> 5;       // row-in-block, f-slot
    const float* px = x + b * 131072 + r0 + rl;
    float ss = 0.f;
#pragma unroll
    for (int j = 0; j < 16; ++j) {
        int f = fp * 16 + j;
        float v = px[f * 1024];
        ldsf[f][rl] = v;
        ss = fmaf(v, v, ss);
    }
    ssred[fp][rl] = ss;
    __syncthreads();
    if (tid < 32) {
        float s = 0.f;
#pragma unroll
        for (int k = 0; k < 8; ++k) s += ssred[k][tid];
        invs[tid] = 1.0f / fmaxf(sqrtf(s), 1e-12f);
    }
    __syncthreads();
    {   // one 16B chunk per thread, consecutive tid -> consecutive chunks
        const int c   = tid;
        const int rgl = c >> 7;                   // local row-group 0..1
        const int cc  = c & 127;                  // chunk within row-group
        const int t8  = (cc >> 6) & 1, q = (cc >> 4) & 3, r = cc & 15;
        const int row = rgl * 16 + r;             // local row 0..31
        const float inv = invs[row];
        union { unsigned int w[4]; int4 v; } u;
#pragma unroll
        for (int half = 0; half < 2; ++half) {
            const int k0 = t8 * 64 + half * 32 + q * 8;
            u.w[half * 2 + 0] = pk_fp8(ldsf[k0 + 0][row] * inv, ldsf[k0 + 1][row] * inv,
                                       ldsf[k0 + 2][row] * inv, ldsf[k0 + 3][row] * inv);
            u.w[half * 2 + 1] = pk_fp8(ldsf[k0 + 4][row] * inv, ldsf[k0 + 5][row] * inv,
                                       ldsf[k0 + 6][row] * inv, ldsf[k0 + 7][row] * inv);
        }
        const int rgg = blockIdx.x * 2 + rgl;     // global row-group
        ((int4*)Xs)[rgg * 128 + cc] = u.v;
    }
}

// ---------------------------------------------------------------------------
// Kernel 2: LDS macro-tile gram. Block bk -> upper-tri macro (I,J), 128x128.
// Stage A panel (rgs I*8..+7, 16KB) and B panel (rgs J*8..+7) into LDS with
// 4 (or 8) independent 16B/thread copies; one barrier; 4 waves compute the
// 2x2 sub-tiles (each wave: quarter rows ga, quarter cols gb of every sub).
// A fragments for both row-subs held in registers; B re-read per tj.
// ---------------------------------------------------------------------------
__global__ __launch_bounds__(256)
void gram_lse_kernel(const i64x2* __restrict__ Xs, float* __restrict__ partials) {
    const int bk = blockIdx.x;
    const int tid = threadIdx.x;
    const int lane = tid & 63, w = tid >> 6;
    const int ga = (w & 1) * 2;                  // A rg offset within sub-tile
    const int gb = (w >> 1) * 2;                 // B rg offset within sub-tile
    const int quad = lane >> 4, colL = lane & 15;
    const float C = 14.426950408889634f;         // 10*log2(e)

    // closed-form macro decode: tiles_before(I) = I*(129-I)/2  (64 rows)
    int I;
    {
        const int t = bk;
        I = (int)((129.0 - sqrt(16641.0 - 8.0 * (double)t)) * 0.5);
        if (I < 0) I = 0;
        while ((((I + 1) * (128 - I)) >> 1) <= t) ++I;   // tb(I+1) <= t
        while (((I * (129 - I)) >> 1) > t) --I;          // tb(I)   >  t
    }
    const int J = I + (bk - ((I * (129 - I)) >> 1));
    const bool diagM = (I == J);

    __shared__ i64x2 ldsA[1024];                 // 16KB: A panel (8 rgs)
    __shared__ i64x2 ldsB[1024];                 // 16KB: B panel (8 rgs)
    {
        const i64x2* pa = Xs + I * 1024;         // panel = contiguous Xs slice
        if (diagM) {
#pragma unroll
            for (int i = 0; i < 4; ++i)
                ldsA[tid + i * 256] = pa[tid + i * 256];
        } else {
            const i64x2* pb = Xs + J * 1024;
#pragma unroll
            for (int i = 0; i < 4; ++i) {
                ldsA[tid + i * 256] = pa[tid + i * 256];
                ldsB[tid + i * 256] = pb[tid + i * 256];
            }
        }
    }
    __syncthreads();
    const i64x2* lb = diagM ? ldsA : ldsB;

    // A fragments for both row sub-tiles, register-resident (32 VGPR)
    i64x2 avv[2][2][2];
#pragma unroll
    for (int ti = 0; ti < 2; ++ti)
#pragma unroll
        for (int g = 0; g < 2; ++g)
#pragma unroll
            for (int t8 = 0; t8 < 2; ++t8)
                avv[ti][g][t8] = ldsA[(ti * 4 + ga + g) * 128 + t8 * 64 + lane];

    float wsum = 0.f;
#pragma unroll
    for (int tj = 0; tj < 2; ++tj) {
        i64x2 bvv[2][2];
#pragma unroll
        for (int g = 0; g < 2; ++g)
#pragma unroll
            for (int t8 = 0; t8 < 2; ++t8)
                bvv[g][t8] = lb[(tj * 4 + gb + g) * 128 + t8 * 64 + lane];

#pragma unroll
        for (int ti = 0; ti < 2; ++ti) {
            if (diagM && ti > tj) continue;      // below-diagonal sub: skip
            const bool dsub = diagM && (ti == tj);

            f32x4 acc[2][2];
#pragma unroll
            for (int i = 0; i < 2; ++i)
#pragma unroll
                for (int j = 0; j < 2; ++j) acc[i][j] = (f32x4){0.f, 0.f, 0.f, 0.f};
#pragma unroll
            for (int t = 0; t < 4; ++t) {        // K-steps of 32
                const int th = t >> 1, tl = t & 1;
                long aL[2], bL[2];
#pragma unroll
                for (int g = 0; g < 2; ++g) {
                    aL[g] = avv[ti][g][th][tl];
                    bL[g] = bvv[g][th][tl];
                }
#pragma unroll
                for (int i = 0; i < 2; ++i)
#pragma unroll
                    for (int j = 0; j < 2; ++j)
                        acc[i][j] = __builtin_amdgcn_mfma_f32_16x16x32_fp8_fp8(
                            aL[i], bL[j], acc[i][j], 0, 0, 0);
            }

            // C/D: col=lane&15, row=(lane>>4)*4+reg (verified)
            float lsum = 0.f;
#pragma unroll
            for (int i = 0; i < 2; ++i) {
                const int rbase = (ga + i) * 16 + quad * 4;   // row in sub-tile
#pragma unroll
                for (int j = 0; j < 2; ++j) {
                    const int cbase = (gb + j) * 16 + colL;   // col in sub-tile
#pragma unroll
                    for (int g = 0; g < 4; ++g) {
                        if (dsub && (rbase + g == cbase)) continue;
                        lsum += EXP2F(fmaf(C, acc[i][j][g], -C));
                    }
                }
            }
            wsum += dsub ? lsum : 2.0f * lsum;   // symmetry weight
        }
    }

#pragma unroll
    for (int o = 32; o > 0; o >>= 1) wsum += __shfl_down(wsum, o, 64);
    __shared__ float red[4];
    if (lane == 0) red[w] = wsum;
    __syncthreads();
    if (tid == 0) partials[bk] = red[0] + red[1] + red[2] + red[3];
}

// ---------------------------------------------------------------------------
// Kernel 3: out = 10 + ln(sum of 2080 partials), f64 accumulation.
// ---------------------------------------------------------------------------
__global__ __launch_bounds__(256)
void final_kernel(const float* __restrict__ partials, float* __restrict__ out) {
    double s = 0.0;
    for (int i = threadIdx.x; i < NMACR; i += 256) s += (double)partials[i];
#pragma unroll
    for (int o = 32; o > 0; o >>= 1) s += __shfl_down(s, o, 64);
    __shared__ double red[4];
    if ((threadIdx.x & 63) == 0) red[threadIdx.x >> 6] = s;
    __syncthreads();
    if (threadIdx.x == 0)
        out[0] = (float)(10.0 + log(red[0] + red[1] + red[2] + red[3]));
}

extern "C" void kernel_launch(void* const* d_in, const int* in_sizes, int n_in,
                              void* d_out, int out_size, void* d_ws, size_t ws_size,
                              hipStream_t stream) {
    const float* x = (const float*)d_in[0];
    float* out = (float*)d_out;
    float* partials = (float*)d_ws;                         // 2080 floats
    unsigned char* Xs = (unsigned char*)d_ws + 131072;      // 1MB fp8 X̂

    normalize_kernel<<<256, 256, 0, stream>>>(x, Xs);
    gram_lse_kernel<<<NMACR, 256, 0, stream>>>((const i64x2*)Xs, partials);
    final_kernel<<<1, 256, 0, stream>>>(partials, out);
}